// Round 3
// baseline (358.670 us; speedup 1.0000x reference)
//
#include <hip/hip_runtime.h>
#include <math.h>

#define S_N 8
#define U_N 8
#define K_N 6
#define NNEG 17
#define ZDIM 64
#define CDIM 256
#define LEN 512
#define TDIM (LEN + K_N)   // 518

// Fused CPC loss kernel.
// grid = K*S*U*8 = 3072 blocks, 256 threads.
// Block bid: lt8 = bid&7 (l-tile of 64), su = (bid>>3)&63, k = bid>>9.
// Phase 1: Wc[ll][z] = sum_c c[su][l0+ll][c] * W[k][z][c] + b[k][z]   (LDS GEMM, 4x4 reg tile)
// Phase 2: 18 logits per l (1 pos + 17 gathered negs), logsumexp + argmax, block-reduce, atomicAdd.

__global__ __launch_bounds__(256) void cpc_fused(
    const float* __restrict__ zg, const float* __restrict__ cg_,
    const float* __restrict__ Wg, const float* __restrict__ bg,
    const int* __restrict__ bidx, const int* __restrict__ sidx,
    float* __restrict__ out)
{
    __shared__ float cs_t[64][64];  // [cc][ll], XOR-swizzled columns
    __shared__ float w_t[64][64];   // [cc][z],  XOR-swizzled columns
    __shared__ float wc[64][68];    // [ll][z],  +4 pad to break bank stride
    __shared__ float red[8];

    const int tid = threadIdx.x;
    const int bid = blockIdx.x;
    const int lt8 = bid & 7;
    const int su  = (bid >> 3) & 63;
    const int k   = bid >> 9;
    const int s   = su >> 3;
    const int u   = su & 7;
    const int l0  = lt8 * 64;

    const int tz = tid & 15;   // z-group (4 z per thread)
    const int tl = tid >> 4;   // l-group (4 l per thread)

    float acc[4][4] = {};

    const int half = tid >> 2;  // 0..63: row (ll or z) this thread stages
    const int cgq  = tid & 3;   // which 64-byte column chunk

    // ---------------- Phase 1: GEMM over c in 4 chunks of 64 ----------------
    for (int c0 = 0; c0 < 4; ++c0) {
        // stage c tile, transposed [cc][ll], swizzle column by ((cc>>3)&7)<<2
        {
            const float* src = cg_ + ((size_t)(su * TDIM + l0 + half)) * CDIM + c0 * 64 + cgq * 16;
            #pragma unroll
            for (int q = 0; q < 4; ++q) {
                float4 v = *(const float4*)(src + q * 4);
                float vv[4] = {v.x, v.y, v.z, v.w};
                #pragma unroll
                for (int j = 0; j < 4; ++j) {
                    int cc = cgq * 16 + q * 4 + j;
                    int sw = ((cc >> 3) & 7) << 2;
                    cs_t[cc][half ^ sw] = vv[j];
                }
            }
        }
        // stage W tile, transposed [cc][z], same swizzle
        {
            const float* src = Wg + ((size_t)(k * ZDIM + half)) * CDIM + c0 * 64 + cgq * 16;
            #pragma unroll
            for (int q = 0; q < 4; ++q) {
                float4 v = *(const float4*)(src + q * 4);
                float vv[4] = {v.x, v.y, v.z, v.w};
                #pragma unroll
                for (int j = 0; j < 4; ++j) {
                    int cc = cgq * 16 + q * 4 + j;
                    int sw = ((cc >> 3) & 7) << 2;
                    w_t[cc][half ^ sw] = vv[j];
                }
            }
        }
        __syncthreads();
        #pragma unroll 8
        for (int cc = 0; cc < 64; ++cc) {
            int sw = ((cc >> 3) & 7) << 2;
            float4 av = *(const float4*)&cs_t[cc][(tl * 4) ^ sw];
            float4 bv = *(const float4*)&w_t[cc][(tz * 4) ^ sw];
            float aa[4] = {av.x, av.y, av.z, av.w};
            float bb[4] = {bv.x, bv.y, bv.z, bv.w};
            #pragma unroll
            for (int i = 0; i < 4; ++i)
                #pragma unroll
                for (int j = 0; j < 4; ++j)
                    acc[i][j] = fmaf(aa[i], bb[j], acc[i][j]);
        }
        __syncthreads();
    }

    // bias + write Wc tile to LDS
    {
        float4 bv = *(const float4*)(bg + k * ZDIM + tz * 4);
        float bb[4] = {bv.x, bv.y, bv.z, bv.w};
        #pragma unroll
        for (int i = 0; i < 4; ++i) {
            float4 o;
            o.x = acc[i][0] + bb[0];
            o.y = acc[i][1] + bb[1];
            o.z = acc[i][2] + bb[2];
            o.w = acc[i][3] + bb[3];
            *(float4*)&wc[tl * 4 + i][tz * 4] = o;
        }
    }
    __syncthreads();

    // ---------------- Phase 2: logits, logsumexp, reduce ----------------
    const int lt = tid >> 2;   // l within tile
    const int jq = tid & 3;    // 4 lanes split the 18 logits: j = jq + 4*t
    const int l  = l0 + lt;

    float fv[5];
    #pragma unroll
    for (int t = 0; t < 5; ++t) {
        int j = jq + 4 * t;
        if (j >= 18) { fv[t] = -1e30f; continue; }
        const float* zp;
        if (j == 0) {
            zp = zg + ((size_t)(su * TDIM + (k + 1 + l))) * ZDIM;
        } else {
            int n  = j - 1;
            int bi = bidx[(k * U_N + u) * NNEG + n];
            int si = sidx[(size_t)((((k * S_N + s) * U_N + u) * NNEG + n)) * LEN + l];
            zp = zg + ((size_t)((s * U_N + bi) * TDIM + (k + 1 + si))) * ZDIM;
        }
        float f = 0.f;
        const float* wr = &wc[lt][0];
        #pragma unroll
        for (int c4 = 0; c4 < 16; ++c4) {
            float4 zv = *(const float4*)(zp + c4 * 4);
            float4 wv = *(const float4*)(wr + c4 * 4);
            f = fmaf(zv.x, wv.x, f);
            f = fmaf(zv.y, wv.y, f);
            f = fmaf(zv.z, wv.z, f);
            f = fmaf(zv.w, wv.w, f);
        }
        fv[t] = f * 0.125f;
    }

    float mall = -1e30f, mneg = -1e30f;
    #pragma unroll
    for (int t = 0; t < 5; ++t) {
        mall = fmaxf(mall, fv[t]);
        bool skip = (jq == 0 && t == 0) || (jq + 4 * t >= 18);
        if (!skip) mneg = fmaxf(mneg, fv[t]);
    }
    mall = fmaxf(mall, __shfl_xor(mall, 1));
    mall = fmaxf(mall, __shfl_xor(mall, 2));
    mneg = fmaxf(mneg, __shfl_xor(mneg, 1));
    mneg = fmaxf(mneg, __shfl_xor(mneg, 2));

    float se = 0.f;
    #pragma unroll
    for (int t = 0; t < 5; ++t) {
        if (jq + 4 * t < 18) se += __expf(fv[t] - mall);
    }
    se += __shfl_xor(se, 1);
    se += __shfl_xor(se, 2);

    float lossv = 0.f, accv = 0.f;
    if (jq == 0) {
        lossv = (mall + __logf(se)) - fv[0];
        accv  = (fv[0] >= mneg) ? 1.f : 0.f;
    }

    // block reduce (wave shuffle + LDS across 4 waves)
    #pragma unroll
    for (int off = 1; off < 64; off <<= 1) {
        lossv += __shfl_xor(lossv, off);
        accv  += __shfl_xor(accv, off);
    }
    const int wv = tid >> 6;
    if ((tid & 63) == 0) { red[wv * 2] = lossv; red[wv * 2 + 1] = accv; }
    __syncthreads();
    if (tid == 0) {
        float ls = red[0] + red[2] + red[4] + red[6];
        float ac = red[1] + red[3] + red[5] + red[7];
        atomicAdd(out, ls * (1.0f / 196608.0f));          // mean over K*S*U*L
        atomicAdd(out + 1 + k, ac * (1.0f / 32768.0f));   // mean over S*U*L
    }
}

extern "C" void kernel_launch(void* const* d_in, const int* in_sizes, int n_in,
                              void* d_out, int out_size, void* d_ws, size_t ws_size,
                              hipStream_t stream) {
    const float* z = (const float*)d_in[0];
    const float* c = (const float*)d_in[1];
    const float* W = (const float*)d_in[2];
    const float* b = (const float*)d_in[3];
    const int* batch_index = (const int*)d_in[4];
    const int* seq_index   = (const int*)d_in[5];
    float* out = (float*)d_out;

    hipMemsetAsync(out, 0, 7 * sizeof(float), stream);
    dim3 grid(K_N * S_N * U_N * 8);  // 3072
    cpc_fused<<<grid, dim3(256), 0, stream>>>(z, c, W, b, batch_index, seq_index, out);
}